// Round 9
// baseline (508.457 us; speedup 1.0000x reference)
//
#include <hip/hip_runtime.h>
#include <math.h>

#define B_ 4
#define T_ 16
#define H_ 64
#define W_ 64
#define CIN 32
#define CO 64
#define PXS 40   // padded per-pixel stride in shorts (80 B)

typedef __attribute__((ext_vector_type(8))) short bf16x8;
typedef __attribute__((ext_vector_type(4))) float f32x4;

__device__ __forceinline__ float hsig(float z) {
    return fminf(1.f, fmaxf(0.f, 0.2f * z + 0.5f));
}

// fast tanh: v_exp_f32 + v_rcp_f32. Saturation exact at +/-inf.
__device__ __forceinline__ float ftanh(float x) {
    float e = __builtin_amdgcn_exp2f(x * 2.8853900817779268f);  // 2*log2(e)
    return 1.f - 2.f * __builtin_amdgcn_rcpf(e + 1.f);
}

__device__ __forceinline__ unsigned short f2bf(float f) {
    union { float f; unsigned u; } v; v.f = f;
    unsigned r = v.u + 0x7FFFu + ((v.u >> 16) & 1u);   // RTNE
    return (unsigned short)(r >> 16);
}

// 16B device-coherent load (bypasses L1/L2 -> sees remote XCD writes at L3).
__device__ __forceinline__ uint4 ldg_coh16(const unsigned short* p) {
    uint4 v;
    asm volatile("global_load_dwordx4 %0, %1, off sc0 sc1\n\t"
                 "s_waitcnt vmcnt(0)"
                 : "=v"(v) : "v"(p) : "memory");
    return v;
}
// 2B device-coherent store (write-through to coherence point).
__device__ __forceinline__ void stg_coh16b(unsigned short* p, unsigned short d) {
    unsigned dd = d;
    asm volatile("global_store_short %0, %1, off sc0 sc1" :: "v"(p), "v"(dd) : "memory");
}

// Transpose+convert weights once per launch; zero the tile flags.
//   wkT[kpos][n=256][k=32]       from wk (3,3,32,256)
//   wrT[kpos][q=2][n=256][k=32]  from wr (3,3,64,256)
__global__ void transform_weights(const float* __restrict__ wk,
                                  const float* __restrict__ wr,
                                  unsigned short* __restrict__ wkT,
                                  unsigned short* __restrict__ wrT,
                                  int* __restrict__ flags)
{
    int i = blockIdx.x * 256 + threadIdx.x;
    if (i < 9 * 256 * 32) {
        int k = i & 31, n = (i >> 5) & 255, kpos = i >> 13;
        wkT[i] = f2bf(wk[(kpos * 32 + k) * 256 + n]);
    }
    if (i < 9 * 2 * 256 * 32) {
        int k = i & 31, n = (i >> 5) & 255, q = (i >> 13) & 1, kpos = i >> 14;
        wrT[i] = f2bf(wr[(kpos * 64 + q * 32 + k) * 256 + n]);
    }
    if (i < 256 * 16) flags[i] = 0;
}

// Persistent kernel: all 16 timesteps in ONE dispatch. 256 blocks (1/CU,
// co-resident), 768 threads = 12 waves = 3 wave-groups x 4 n-slices.
// Per step: R8's 3-way k-split (wg0: x-conv 0-8; wg1: h q 9-17; wg2: 18-26),
// 3-way LDS merge, per-wg epilogue rows {0,1},{2},{3}.
// Cross-block h exchange: sc0sc1 coherent 16B loads / 2B stores (bypass the
// non-coherent per-XCD L2); neighbor ordering via monotonic agent-scope flags
// (R2 protocol, proven correct). c state NEVER leaves VGPRs (cpv, literal idx).
// Weights/x ride the warm L2 (no kernel boundaries -> never invalidated).
__global__ __launch_bounds__(768, 3)
void convlstm_persist(const float* __restrict__ x,
                      const unsigned short* __restrict__ wkT,
                      const unsigned short* __restrict__ wrT,
                      const float* __restrict__ bias,
                      const float* __restrict__ gamma,
                      const float* __restrict__ beta,
                      const float* __restrict__ mean,
                      const float* __restrict__ var,
                      unsigned short* __restrict__ h0,
                      unsigned short* __restrict__ h1,
                      int* __restrict__ flags,
                      float* __restrict__ out)
{
    __shared__ __align__(16) unsigned short sx[6 * 18 * PXS];
    __shared__ __align__(16) unsigned short shm[2][6 * 18 * PXS];
    // slots: row0:{wg1->0,wg2->1} row1:{wg1->2,wg2->3} row2:{wg0->4,wg2->5} row3:{wg0->6,wg1->7}
    __shared__ __align__(16) float axx[4 * 4 * 8 * 256];

    const int tid = threadIdx.x;
    const int wv = tid >> 6, lane = tid & 63;
    const int ln = lane & 15, kg = lane >> 4;
    const int wg = wv >> 2;
    const int sl = wv & 3;

    const int bi = blockIdx.x;
    const int b = bi >> 6, tile = bi & 63;
    const int ty = tile >> 2, tx = tile & 3;
    const int oy = ty * 4, ox = tx * 16;

    unsigned short* sh0 = shm[0];
    unsigned short* sh1 = shm[1];

    // neighbor flag pointers (threads 0..7, 8 spatial neighbors, same b)
    int* nbf = nullptr;
    if (tid < 8) {
        int k = tid + (tid >= 4 ? 1 : 0);
        int dy = k / 3 - 1, dx = k - (k / 3) * 3 - 1;
        int ny = ty + dy, nx = tx + dx;
        if (ny >= 0 && ny < 16 && nx >= 0 && nx < 4)
            nbf = flags + ((b * 64 + ny * 4 + nx) << 4);
    }
    int* myflag = flags + (bi << 4);

    const int ch = sl * 16 + ln;
    const unsigned short* wkp = wkT + (size_t)ch * 32 + kg * 8;
    const unsigned short* wrp = wrT + (size_t)ch * 32 + kg * 8;

    const float bi0 = bias[ch], bi1 = bias[64 + ch], bi2 = bias[128 + ch], bi3 = bias[192 + ch];
    const float inv = gamma[ch] * rsqrtf(var[ch] + 1e-3f);
    const float shift = beta[ch] - mean[ch] * inv;

    // persistent c state: wg0 rows {0,1} -> cpv[0],cpv[1]; wg1 row2 / wg2 row3 -> cpv[0]
    float cpv[2][4];
#pragma unroll
    for (int rr = 0; rr < 2; ++rr)
#pragma unroll
        for (int reg = 0; reg < 4; ++reg) cpv[rr][reg] = 0.f;

#pragma unroll 1
    for (int t = 0; t < T_; ++t) {
        const unsigned short* hinp = (t & 1) ? h0 : h1;
        unsigned short* houtp      = (t & 1) ? h1 : h0;

        // ---- wg2 stages x(t) (normal cached loads) while wg0's threads 0-7 spin ----
        if (wg == 2) {
#pragma unroll
            for (int i = 0; i < 2; ++i) {
                int e = (tid - 512) + i * 256;
                if (e < 432) {
                    int c8 = e & 3, p = e >> 2;
                    int row = p / 18, col = p - row * 18;
                    int gy = oy - 1 + row, gx = ox - 1 + col;
                    float4 v0 = make_float4(0.f, 0.f, 0.f, 0.f), v1 = v0;
                    if ((unsigned)gy < (unsigned)H_ && (unsigned)gx < (unsigned)W_) {
                        const float* p32 = &x[((((size_t)b * T_ + t) * H_ + gy) * W_ + gx) * CIN + c8 * 8];
                        v0 = *(const float4*)p32; v1 = *(const float4*)(p32 + 4);
                    }
                    unsigned short* d = &sx[(row * 18 + col) * PXS + c8 * 8];
                    d[0] = f2bf(v0.x); d[1] = f2bf(v0.y); d[2] = f2bf(v0.z); d[3] = f2bf(v0.w);
                    d[4] = f2bf(v1.x); d[5] = f2bf(v1.y); d[6] = f2bf(v1.z); d[7] = f2bf(v1.w);
                }
            }
        }
        // ---- wait for the 8 neighbors to have published h(t-1) ----
        if (t > 0 && nbf) {
            while (__hip_atomic_load(nbf, __ATOMIC_RELAXED, __HIP_MEMORY_SCOPE_AGENT) < t)
                __builtin_amdgcn_s_sleep(2);
        }
        __syncthreads();   // spin done; safe to read remote h via coherent loads

        // ---- wg0+wg1 stage h(t-1) halo: 864 x 16B coherent loads ----
        if (t > 0 && wg < 2) {
#pragma unroll
            for (int i = 0; i < 2; ++i) {
                int e = tid + i * 512;
                if (e < 864) {
                    int o = e & 7, p = e >> 3;
                    int row = p / 18, col = p - row * 18;
                    int gy = oy - 1 + row, gx = ox - 1 + col;
                    uint4 v = make_uint4(0u, 0u, 0u, 0u);
                    if ((unsigned)gy < (unsigned)H_ && (unsigned)gx < (unsigned)W_)
                        v = ldg_coh16(&hinp[(((size_t)b * H_ + gy) * W_ + gx) * CO + o * 8]);
                    int q = o >> 2, s4 = o & 3;
                    *(uint4*)&shm[q][(row * 18 + col) * PXS + s4 * 8] = v;
                }
            }
        }
        __syncthreads();   // sx + shm ready

        f32x4 acc[4][4];   // LITERAL indices only (rule #20)
#pragma unroll
        for (int g = 0; g < 4; ++g)
#pragma unroll
            for (int r = 0; r < 4; ++r) acc[g][r] = (f32x4){0.f, 0.f, 0.f, 0.f};

#define WPTR(c) ((c) < 9 ? (wkp + (size_t)(c) * 8192) : (wrp + (size_t)((c) - 9) * 8192))
#define SRCB(c) ((c) < 9 ? sx : ((((c) - 9) & 1) ? sh1 : sh0))
#define KP(c)   ((c) < 9 ? (c) : (((c) - 9) >> 1))

#define CHUNK(c) {                                                               \
    const unsigned short* wp_ = WPTR(c);                                         \
    bf16x8 w0 = *(const bf16x8*)(wp_);                                           \
    bf16x8 w1 = *(const bf16x8*)(wp_ + 2048);                                    \
    bf16x8 w2 = *(const bf16x8*)(wp_ + 4096);                                    \
    bf16x8 w3 = *(const bf16x8*)(wp_ + 6144);                                    \
    const int ky_ = KP(c) / 3, kx_ = KP(c) - (KP(c) / 3) * 3;                    \
    const unsigned short* sb_ = SRCB(c);                                         \
    bf16x8 a0 = *(const bf16x8*)&sb_[((0 + ky_) * 18 + ln + kx_) * PXS + kg * 8];\
    bf16x8 a1 = *(const bf16x8*)&sb_[((1 + ky_) * 18 + ln + kx_) * PXS + kg * 8];\
    bf16x8 a2 = *(const bf16x8*)&sb_[((2 + ky_) * 18 + ln + kx_) * PXS + kg * 8];\
    bf16x8 a3 = *(const bf16x8*)&sb_[((3 + ky_) * 18 + ln + kx_) * PXS + kg * 8];\
    __builtin_amdgcn_s_setprio(1);                                               \
    acc[0][0] = __builtin_amdgcn_mfma_f32_16x16x32_bf16(a0, w0, acc[0][0], 0, 0, 0); \
    acc[0][1] = __builtin_amdgcn_mfma_f32_16x16x32_bf16(a1, w0, acc[0][1], 0, 0, 0); \
    acc[0][2] = __builtin_amdgcn_mfma_f32_16x16x32_bf16(a2, w0, acc[0][2], 0, 0, 0); \
    acc[0][3] = __builtin_amdgcn_mfma_f32_16x16x32_bf16(a3, w0, acc[0][3], 0, 0, 0); \
    acc[1][0] = __builtin_amdgcn_mfma_f32_16x16x32_bf16(a0, w1, acc[1][0], 0, 0, 0); \
    acc[1][1] = __builtin_amdgcn_mfma_f32_16x16x32_bf16(a1, w1, acc[1][1], 0, 0, 0); \
    acc[1][2] = __builtin_amdgcn_mfma_f32_16x16x32_bf16(a2, w1, acc[1][2], 0, 0, 0); \
    acc[1][3] = __builtin_amdgcn_mfma_f32_16x16x32_bf16(a3, w1, acc[1][3], 0, 0, 0); \
    acc[2][0] = __builtin_amdgcn_mfma_f32_16x16x32_bf16(a0, w2, acc[2][0], 0, 0, 0); \
    acc[2][1] = __builtin_amdgcn_mfma_f32_16x16x32_bf16(a1, w2, acc[2][1], 0, 0, 0); \
    acc[2][2] = __builtin_amdgcn_mfma_f32_16x16x32_bf16(a2, w2, acc[2][2], 0, 0, 0); \
    acc[2][3] = __builtin_amdgcn_mfma_f32_16x16x32_bf16(a3, w2, acc[2][3], 0, 0, 0); \
    acc[3][0] = __builtin_amdgcn_mfma_f32_16x16x32_bf16(a0, w3, acc[3][0], 0, 0, 0); \
    acc[3][1] = __builtin_amdgcn_mfma_f32_16x16x32_bf16(a1, w3, acc[3][1], 0, 0, 0); \
    acc[3][2] = __builtin_amdgcn_mfma_f32_16x16x32_bf16(a2, w3, acc[3][2], 0, 0, 0); \
    acc[3][3] = __builtin_amdgcn_mfma_f32_16x16x32_bf16(a3, w3, acc[3][3], 0, 0, 0); \
    __builtin_amdgcn_s_setprio(0); }

        if (wg == 0) {
            CHUNK(0) CHUNK(1) CHUNK(2) CHUNK(3) CHUNK(4) CHUNK(5) CHUNK(6) CHUNK(7) CHUNK(8)
        } else if (wg == 1) {
            if (t > 0) {
                CHUNK(9) CHUNK(10) CHUNK(11) CHUNK(12) CHUNK(13) CHUNK(14) CHUNK(15) CHUNK(16) CHUNK(17)
            }
        } else {
            if (t > 0) {
                CHUNK(18) CHUNK(19) CHUNK(20) CHUNK(21) CHUNK(22) CHUNK(23) CHUNK(24) CHUNK(25) CHUNK(26)
            }
        }

        const int axo = (ln << 4) + (kg << 2);
#define AXPUB(s, G, R) *(f32x4*)&axx[(((sl * 4 + (G)) * 8 + (s)) << 8) + axo] = acc[G][R];
#define AXRD(s, G)     (*(const f32x4*)&axx[(((sl * 4 + (G)) * 8 + (s)) << 8) + axo])

        if (wg == 0) {
#pragma unroll
            for (int g = 0; g < 4; ++g) { AXPUB(4, g, 2) AXPUB(6, g, 3) }
        } else if (wg == 1) {
#pragma unroll
            for (int g = 0; g < 4; ++g) { AXPUB(0, g, 0) AXPUB(2, g, 1) AXPUB(7, g, 3) }
        } else {
#pragma unroll
            for (int g = 0; g < 4; ++g) { AXPUB(1, g, 0) AXPUB(3, g, 1) AXPUB(5, g, 2) }
        }
        __syncthreads();

        // ---- merge + epilogue, literal rows; c stays in cpv (literal CPI) ----
#define EPI(R, CPI, S0, S1) {                                                    \
        const int gy = oy + (R);                                                 \
        f32x4 av[4];                                                             \
        _Pragma("unroll")                                                        \
        for (int g = 0; g < 4; ++g)                                              \
            av[g] = acc[g][R] + AXRD(S0, g) + AXRD(S1, g);                       \
        _Pragma("unroll")                                                        \
        for (int reg = 0; reg < 4; ++reg) {                                      \
            const int gx = ox + kg * 4 + reg;                                    \
            size_t pix = ((size_t)b * H_ + gy) * W_ + gx;                        \
            float ig = hsig(av[0][reg] + bi0);                                   \
            float fg = hsig(av[1][reg] + bi1);                                   \
            float cg = ftanh(av[2][reg] + bi2);                                  \
            float og = hsig(av[3][reg] + bi3);                                   \
            float cv = fg * cpv[CPI][reg] + ig * cg;                             \
            cpv[CPI][reg] = cv;                                                  \
            float hv = og * ftanh(cv);                                           \
            stg_coh16b(&houtp[pix * CO + ch], f2bf(hv));                         \
            __builtin_nontemporal_store(hv * inv + shift,                        \
                &out[((((size_t)b * T_ + t) * H_ + gy) * W_ + gx) * CO + ch]);   \
        }                                                                        \
    }

        if (wg == 0)      { EPI(0, 0, 0, 1) EPI(1, 1, 2, 3) }
        else if (wg == 1) { EPI(2, 0, 4, 5) }
        else              { EPI(3, 0, 6, 7) }
#undef EPI
#undef AXPUB
#undef AXRD
#undef CHUNK
#undef WPTR
#undef SRCB
#undef KP

        // ---- publish: barrier drains all waves' h-stores, then flag ----
        __syncthreads();
        if (tid == 0)
            __hip_atomic_store(myflag, t + 1, __ATOMIC_RELAXED, __HIP_MEMORY_SCOPE_AGENT);
    }
}

extern "C" void kernel_launch(void* const* d_in, const int* in_sizes, int n_in,
                              void* d_out, int out_size, void* d_ws, size_t ws_size,
                              hipStream_t stream)
{
    (void)in_sizes; (void)n_in; (void)out_size; (void)ws_size;
    const float* x     = (const float*)d_in[0];
    const float* wk    = (const float*)d_in[1];
    const float* wr    = (const float*)d_in[2];
    const float* bias  = (const float*)d_in[3];
    const float* gamma = (const float*)d_in[4];
    const float* beta  = (const float*)d_in[5];
    const float* mean  = (const float*)d_in[6];
    const float* var   = (const float*)d_in[7];
    float* out = (float*)d_out;

    const size_t plane = (size_t)B_ * H_ * W_ * CO;           // 1,048,576 elems
    unsigned short* h0 = (unsigned short*)d_ws;               // bf16, 2 MB
    unsigned short* h1 = h0 + plane;                          // bf16, 2 MB
    unsigned short* wkT = h1 + plane;                         // 147 KB
    unsigned short* wrT = wkT + 9 * 256 * 32;                 // 295 KB
    int* flags = (int*)(wrT + 9 * 2 * 256 * 32);              // 16 KB

    transform_weights<<<576, 256, 0, stream>>>(wk, wr, wkT, wrT, flags);
    convlstm_persist<<<256, 768, 0, stream>>>(x, wkT, wrT, bias, gamma, beta, mean, var,
                                              h0, h1, flags, out);
}

// Round 10
// 288.231 us; speedup vs baseline: 1.7641x; 1.7641x over previous
//
#include <hip/hip_runtime.h>
#include <math.h>

#define B_ 4
#define T_ 16
#define H_ 64
#define W_ 64
#define CIN 32
#define CO 64
#define NG 256   // 4*CO gate channels
#define PXS 40   // padded per-pixel stride in shorts (80 B): 16B-aligned, spreads LDS banks

typedef __attribute__((ext_vector_type(8))) short bf16x8;
typedef __attribute__((ext_vector_type(4))) float f32x4;

__device__ __forceinline__ float hsig(float z) {
    return fminf(1.f, fmaxf(0.f, 0.2f * z + 0.5f));
}

// fast tanh: v_exp_f32 + v_rcp_f32. Saturation exact at +/-inf.
__device__ __forceinline__ float ftanh(float x) {
    float e = __builtin_amdgcn_exp2f(x * 2.8853900817779268f);  // 2*log2(e)
    return 1.f - 2.f * __builtin_amdgcn_rcpf(e + 1.f);
}

__device__ __forceinline__ unsigned short f2bf(float f) {
    union { float f; unsigned u; } v; v.f = f;
    unsigned r = v.u + 0x7FFFu + ((v.u >> 16) & 1u);   // RTNE
    return (unsigned short)(r >> 16);
}

// nt load of 16B of fp32 (no L2 pollution for read-once streams)
__device__ __forceinline__ f32x4 ntload4(const float* p) {
    return __builtin_nontemporal_load((const f32x4*)p);
}

// Transpose+convert weights once per launch:
//   wkT[kpos][n=256][k=32]        from wk (3,3,32,256)
//   wrT[kpos][q=2][n=256][k=32]   from wr (3,3,64,256), q = cin chunk of 32
__global__ void transform_weights(const float* __restrict__ wk,
                                  const float* __restrict__ wr,
                                  unsigned short* __restrict__ wkT,
                                  unsigned short* __restrict__ wrT)
{
    int i = blockIdx.x * 256 + threadIdx.x;
    if (i < 9 * 256 * 32) {
        int k = i & 31, n = (i >> 5) & 255, kpos = i >> 13;
        wkT[i] = f2bf(wk[(kpos * 32 + k) * 256 + n]);
    }
    if (i < 9 * 2 * 256 * 32) {
        int k = i & 31, n = (i >> 5) & 255, q = (i >> 13) & 1, kpos = i >> 14;
        wrT[i] = f2bf(wr[(kpos * 64 + q * 32 + k) * 256 + n]);
    }
}

// One timestep. Block = 64 px (4 rows x 16 cols), 512 threads = 8 waves.
// Balanced k-split over the 27 (kpos,q) chunks of the fused conv:
//   x-waves (4-7): x-conv (9 chunks) + h-conv q1 kpos 0-4 (5)  = 14 chunks
//   h-waves (0-3): h-conv q0 (9 chunks) + q1 kpos 5-8 (4)      = 13 chunks
// Depth-4 weight-fragment pipeline, literal indices everywhere (rule #20).
// L2-POLLUTION ISOLATION (this round's change): x staging, cprev loads, cbuf
// and out stores all carry nt hints — these streams have zero L2 reuse, and
// keeping them out of L2 keeps the shared 442 KB weight set resident per XCD
// (theory: weight evictions -> L3-latency stalls were the ~8 us/step residual).
// h stays cached (9 blocks re-read it within a step: genuine L2 reuse).
template<bool FIRST>
__global__ __launch_bounds__(512, 2)
void convlstm_step(const float* __restrict__ x,
                   const unsigned short* __restrict__ wkT,
                   const unsigned short* __restrict__ wrT,
                   const float* __restrict__ bias,
                   const float* __restrict__ gamma,
                   const float* __restrict__ beta,
                   const float* __restrict__ mean,
                   const float* __restrict__ var,
                   const unsigned short* __restrict__ hin,   // bf16 NHWC
                   unsigned short* __restrict__ hout,        // bf16 NHWC
                   float* __restrict__ cbuf,
                   float* __restrict__ out,
                   int t)
{
    __shared__ __align__(16) unsigned short sx[6 * 18 * PXS];        //  8.6 KB
    __shared__ __align__(16) unsigned short shm[2][6 * 18 * PXS];    // 17.3 KB
    // partial exchange: [slice4][gate4][row4][ch16][px 16 + 4 pad] fp32 = 80 KB
    __shared__ __align__(16) float axx[4 * 4 * 4 * 16 * 20];

    const int tid = threadIdx.x;
    const int wv = tid >> 6, lane = tid & 63;
    const int ln = lane & 15, kg = lane >> 4;
    const bool hwave = (wv < 4);
    const int sl = wv & 3;                 // n-slice: ch = sl*16 + ln

    const int bi = blockIdx.x;
    const int b = bi >> 6, tile = bi & 63;
    const int oy = (tile >> 2) * 4;        // 16 row-tiles
    const int ox = (tile & 3) * 16;        // 4 col-tiles

    unsigned short* sh0 = shm[0];
    unsigned short* sh1 = shm[1];

    // ---- parallel staging: x-waves stage sx (nt), h-waves stage sh (cached) ----
    if (!hwave) {
        // x halo (fp32 -> bf16): 108 positions x 4 chunks of 8 cin = 432 elems
#pragma unroll
        for (int i = 0; i < 2; ++i) {
            int e = (tid - 256) + i * 256;
            if (e < 432) {
                int c8 = e & 3, p = e >> 2;
                int row = p / 18, col = p - row * 18;
                int gy = oy - 1 + row, gx = ox - 1 + col;
                f32x4 v0 = (f32x4){0.f, 0.f, 0.f, 0.f}, v1 = v0;
                if ((unsigned)gy < (unsigned)H_ && (unsigned)gx < (unsigned)W_) {
                    const float* p32 = &x[((((size_t)b * T_ + t) * H_ + gy) * W_ + gx) * CIN + c8 * 8];
                    v0 = ntload4(p32); v1 = ntload4(p32 + 4);
                }
                unsigned short* d = &sx[(row * 18 + col) * PXS + c8 * 8];
                d[0] = f2bf(v0[0]); d[1] = f2bf(v0[1]); d[2] = f2bf(v0[2]); d[3] = f2bf(v0[3]);
                d[4] = f2bf(v1[0]); d[5] = f2bf(v1[1]); d[6] = f2bf(v1[2]); d[7] = f2bf(v1[3]);
            }
        }
    } else if (!FIRST) {
        // h halo (bf16 copy): 108 positions x 8 octs of 8 ch = 864 elems
#pragma unroll
        for (int i = 0; i < 4; ++i) {
            int e = tid + i * 256;
            if (e < 864) {
                int o = e & 7, p = e >> 3;
                int row = p / 18, col = p - row * 18;
                int gy = oy - 1 + row, gx = ox - 1 + col;
                uint4 v = make_uint4(0u, 0u, 0u, 0u);
                if ((unsigned)gy < (unsigned)H_ && (unsigned)gx < (unsigned)W_)
                    v = *(const uint4*)&hin[(((size_t)b * H_ + gy) * W_ + gx) * CO + o * 8];
                int q = o >> 2, s4 = o & 3;
                *(uint4*)&shm[q][(row * 18 + col) * PXS + s4 * 8] = v;
            }
        }
    }

    const int nbase = sl * 16 + ln;
    const int ch = nbase;
    const unsigned short* wkp = wkT + (size_t)nbase * 32 + kg * 8;
    const unsigned short* wrp = wrT + (size_t)nbase * 32 + kg * 8;

    // ---- hoisted epilogue inputs (both roles, their own row-pair) ----
    // h-waves own rows 0-1, x-waves own rows 2-3 (address math only — values).
    const int rbase = hwave ? 0 : 2;
    const float bi0 = bias[ch], bi1 = bias[64 + ch], bi2 = bias[128 + ch], bi3 = bias[192 + ch];
    const float inv = gamma[ch] * rsqrtf(var[ch] + 1e-3f);
    const float shift = beta[ch] - mean[ch] * inv;
    float cprev[2][4];
    if (!FIRST) {
#pragma unroll
        for (int rr = 0; rr < 2; ++rr)
#pragma unroll
            for (int reg = 0; reg < 4; ++reg) {
                size_t pix = ((size_t)b * H_ + oy + rbase + rr) * W_ + (ox + kg * 4 + reg);
                cprev[rr][reg] = __builtin_nontemporal_load(&cbuf[pix * CO + ch]);
            }
    } else {
#pragma unroll
        for (int rr = 0; rr < 2; ++rr)
#pragma unroll
            for (int reg = 0; reg < 4; ++reg) cprev[rr][reg] = 0.f;
    }

    __syncthreads();

    f32x4 acc[4][4];   // [gate][row-tile] -- LITERAL indices only, everywhere
#pragma unroll
    for (int g = 0; g < 4; ++g)
#pragma unroll
        for (int r = 0; r < 4; ++r) acc[g][r] = (f32x4){0.f, 0.f, 0.f, 0.f};

// ---- chunk maps: literal i only (every use constant-folds) ----
// x-wave: i<9: x-conv kpos=i (src sx);  i>=9: h-conv q1 kpos=i-9 (src sh1)
#define XW_WP(i)  ((i) < 9 ? (wkp + (size_t)(i) * 8192) : (wrp + (size_t)(((i) - 9) * 2 + 1) * 8192))
#define XW_SB(i)  ((i) < 9 ? sx : sh1)
#define XW_KQ(i)  ((i) < 9 ? (i) : (i) - 9)
// h-wave: i<9: h-conv q0 kpos=i (src sh0);  i>=9: q1 kpos=i-4 (src sh1)
#define HW_WP(i)  ((i) < 9 ? (wrp + (size_t)((i) * 2) * 8192) : (wrp + (size_t)(((i) - 4) * 2 + 1) * 8192))
#define HW_SB(i)  ((i) < 9 ? sh0 : sh1)
#define HW_KQ(i)  ((i) < 9 ? (i) : (i) - 4)

#define LOADW(dst, wp) { const unsigned short* wp_ = (wp);        \
    dst[0] = *(const bf16x8*)(wp_);                               \
    dst[1] = *(const bf16x8*)(wp_ + 2048);                        \
    dst[2] = *(const bf16x8*)(wp_ + 4096);                        \
    dst[3] = *(const bf16x8*)(wp_ + 6144); }

#define COMPUTE(i, SBM, KQM, BUF) {                               \
    const int kq_ = KQM(i);                                       \
    const int ky_ = kq_ / 3, kx_ = kq_ - ky_ * 3;                 \
    const unsigned short* sb_ = SBM(i);                           \
    bf16x8 a[4];                                                  \
    _Pragma("unroll")                                             \
    for (int r = 0; r < 4; ++r)                                   \
        a[r] = *(const bf16x8*)&sb_[((r + ky_) * 18 + ln + kx_) * PXS + kg * 8]; \
    __builtin_amdgcn_s_setprio(1);                                \
    _Pragma("unroll")                                             \
    for (int g = 0; g < 4; ++g)                                   \
        _Pragma("unroll")                                         \
        for (int r = 0; r < 4; ++r)                               \
            acc[g][r] = __builtin_amdgcn_mfma_f32_16x16x32_bf16(a[r], BUF[g], acc[g][r], 0, 0, 0); \
    __builtin_amdgcn_s_setprio(0); }

    if (!hwave) {
        constexpr int NCX = FIRST ? 9 : 14;
        bf16x8 P0[4], P1[4], P2[4], P3[4];
        LOADW(P0, XW_WP(0)); LOADW(P1, XW_WP(1)); LOADW(P2, XW_WP(2));
#define XSTEP(i, CUR, NXT)                                        \
        if ((i) < NCX) {                                          \
            if ((i) + 3 < NCX) LOADW(NXT, XW_WP((i) + 3));        \
            COMPUTE(i, XW_SB, XW_KQ, CUR);                        \
        }
        XSTEP(0,  P0, P3)  XSTEP(1,  P1, P0)  XSTEP(2,  P2, P1)  XSTEP(3,  P3, P2)
        XSTEP(4,  P0, P3)  XSTEP(5,  P1, P0)  XSTEP(6,  P2, P1)  XSTEP(7,  P3, P2)
        XSTEP(8,  P0, P3)  XSTEP(9,  P1, P0)  XSTEP(10, P2, P1)  XSTEP(11, P3, P2)
        XSTEP(12, P0, P3)  XSTEP(13, P1, P0)
#undef XSTEP
    } else if (!FIRST) {
        constexpr int NCH = 13;
        bf16x8 P0[4], P1[4], P2[4], P3[4];
        LOADW(P0, HW_WP(0)); LOADW(P1, HW_WP(1)); LOADW(P2, HW_WP(2));
#define HSTEP(i, CUR, NXT)                                        \
        if ((i) < NCH) {                                          \
            if ((i) + 3 < NCH) LOADW(NXT, HW_WP((i) + 3));        \
            COMPUTE(i, HW_SB, HW_KQ, CUR);                        \
        }
        HSTEP(0,  P0, P3)  HSTEP(1,  P1, P0)  HSTEP(2,  P2, P1)  HSTEP(3,  P3, P2)
        HSTEP(4,  P0, P3)  HSTEP(5,  P1, P0)  HSTEP(6,  P2, P1)  HSTEP(7,  P3, P2)
        HSTEP(8,  P0, P3)  HSTEP(9,  P1, P0)  HSTEP(10, P2, P1)  HSTEP(11, P3, P2)
        HSTEP(12, P0, P3)
#undef HSTEP
    }

    // ---- symmetric exchange: LITERAL row indices in each uniform branch ----
    // x-waves publish rows 0,1 (h-waves' epilogue half); h-waves publish 2,3.
    if (!hwave) {
#pragma unroll
        for (int g = 0; g < 4; ++g) {
            *(f32x4*)&axx[((((sl * 4 + g) * 4 + 0) * 16) + ln) * 20 + kg * 4] = acc[g][0];
            *(f32x4*)&axx[((((sl * 4 + g) * 4 + 1) * 16) + ln) * 20 + kg * 4] = acc[g][1];
        }
    } else {
#pragma unroll
        for (int g = 0; g < 4; ++g) {
            *(f32x4*)&axx[((((sl * 4 + g) * 4 + 2) * 16) + ln) * 20 + kg * 4] = acc[g][2];
            *(f32x4*)&axx[((((sl * 4 + g) * 4 + 3) * 16) + ln) * 20 + kg * 4] = acc[g][3];
        }
    }
    __syncthreads();

    // ---- merge + epilogue, literal rows per branch ----
#define EPILOG(R, RR) {                                                          \
        const int gy = oy + (R);                                                 \
        f32x4 av[4];                                                             \
        _Pragma("unroll")                                                        \
        for (int g = 0; g < 4; ++g) {                                            \
            f32x4 v = *(const f32x4*)&axx[((((sl * 4 + g) * 4 + (R)) * 16) + ln) * 20 + kg * 4]; \
            av[g] = acc[g][R] + v;                                               \
        }                                                                        \
        _Pragma("unroll")                                                        \
        for (int reg = 0; reg < 4; ++reg) {                                      \
            const int gx = ox + kg * 4 + reg;                                    \
            size_t pix = ((size_t)b * H_ + gy) * W_ + gx;                        \
            float ig = hsig(av[0][reg] + bi0);                                   \
            float fg = hsig(av[1][reg] + bi1);                                   \
            float cg = ftanh(av[2][reg] + bi2);                                  \
            float og = hsig(av[3][reg] + bi3);                                   \
            float cv = fg * cprev[RR][reg] + ig * cg;                            \
            float hv = og * ftanh(cv);                                           \
            __builtin_nontemporal_store(cv, &cbuf[pix * CO + ch]);               \
            hout[pix * CO + ch] = f2bf(hv);                                      \
            __builtin_nontemporal_store(hv * inv + shift,                        \
                &out[((((size_t)b * T_ + t) * H_ + gy) * W_ + gx) * CO + ch]);   \
        }                                                                        \
    }

    if (hwave) { EPILOG(0, 0) EPILOG(1, 1) }
    else       { EPILOG(2, 0) EPILOG(3, 1) }
#undef EPILOG
}

extern "C" void kernel_launch(void* const* d_in, const int* in_sizes, int n_in,
                              void* d_out, int out_size, void* d_ws, size_t ws_size,
                              hipStream_t stream)
{
    (void)in_sizes; (void)n_in; (void)out_size; (void)ws_size;
    const float* x     = (const float*)d_in[0];
    const float* wk    = (const float*)d_in[1];
    const float* wr    = (const float*)d_in[2];
    const float* bias  = (const float*)d_in[3];
    const float* gamma = (const float*)d_in[4];
    const float* beta  = (const float*)d_in[5];
    const float* mean  = (const float*)d_in[6];
    const float* var   = (const float*)d_in[7];
    float* out = (float*)d_out;

    const size_t plane = (size_t)B_ * H_ * W_ * CO;           // 1,048,576 elems
    unsigned short* h0 = (unsigned short*)d_ws;               // bf16, 2 MB
    unsigned short* h1 = h0 + plane;                          // bf16, 2 MB
    float* cb = (float*)(h1 + plane);                         // fp32, 4 MB
    unsigned short* wkT = (unsigned short*)(cb + plane);      // 147 KB
    unsigned short* wrT = wkT + 9 * 256 * 32;                 // 295 KB

    transform_weights<<<576, 256, 0, stream>>>(wk, wr, wkT, wrT);

    for (int t = 0; t < T_; ++t) {
        const unsigned short* hin = (t & 1) ? h0 : h1;  // garbage at t==0 (unused)
        unsigned short* houtp     = (t & 1) ? h1 : h0;
        if (t == 0)
            convlstm_step<true><<<256, 512, 0, stream>>>(x, wkT, wrT, bias, gamma, beta, mean, var,
                                                         hin, houtp, cb, out, t);
        else
            convlstm_step<false><<<256, 512, 0, stream>>>(x, wkT, wrT, bias, gamma, beta, mean, var,
                                                          hin, houtp, cb, out, t);
    }
}